// Round 11
// baseline (329.005 us; speedup 1.0000x reference)
//
#include <hip/hip_runtime.h>

#define NEG -10000000.0f
#define QSCALE 0.18033688011112042f   // 0.125 (d^-0.5) * log2(e): softmax in exp2 domain

typedef __attribute__((ext_vector_type(8))) short bf16x8;
typedef __attribute__((ext_vector_type(4))) float f32x4;

static __device__ __forceinline__ short f2bf(float f) {
    unsigned int u = __float_as_uint(f);
    unsigned int r = (u + 0x7fffu + ((u >> 16) & 1u)) >> 16;
    return (short)r;
}

// pack two fp32 -> packed bf16x2 (round-half-up; exp outputs, ties measure-zero)
static __device__ __forceinline__ unsigned pack_bf16_2(float a, float b) {
    unsigned ua = __float_as_uint(a) + 0x8000u;
    unsigned ub = __float_as_uint(b) + 0x8000u;
    return __builtin_amdgcn_perm(ub, ua, 0x07060302u);
}

// async global->LDS, 16B per lane. lds base wave-uniform; lane i lands at +16*i.
static __device__ __forceinline__ void async_cp16(const void* g, void* l) {
    __builtin_amdgcn_global_load_lds(
        (const __attribute__((address_space(1))) unsigned int*)g,
        (__attribute__((address_space(3))) unsigned int*)l, 16, 0, 0);
}

// ---------------------------------------------------------------------------
// R14: all prep work in ONE launch (was 3): removes 2 inter-dispatch gaps.
// Block ranges (block-uniform branches, bodies identical to proven kernels):
//   [0,8192)       cvt_bf16 of x -> Xb
//   [8192,12288)   transpose_cvt of W_qkv->Wqt (first 96 cols-tiles) / W_proj->Wpt
//   [12288,12801)  mask_flags + fused pad_flags (block 512)
// ---------------------------------------------------------------------------
__global__ void prep_fused(const float* __restrict__ x, short* __restrict__ Xb,
                           const float* __restrict__ W_qkv, short* __restrict__ Wqt,
                           const float* __restrict__ W_proj, short* __restrict__ Wpt,
                           const int* __restrict__ attn_mask,
                           const int* __restrict__ padding, int* __restrict__ flags) {
    __shared__ float tile[32][33];
    __shared__ int blockok;
    int blk = blockIdx.x, tid = threadIdx.x;

    if (blk < 8192) {                      // ---- cvt_bf16 (n4 = 2097152 exact)
        int i = blk * 256 + tid;
        float4 v = reinterpret_cast<const float4*>(x)[i];
        short4 o;
        o.x = f2bf(v.x); o.y = f2bf(v.y); o.z = f2bf(v.z); o.w = f2bf(v.w);
        reinterpret_cast<short4*>(Xb)[i] = o;
        return;
    }
    if (blk < 12288) {                     // ---- weight transposes (4096 blocks)
        int local = blk - 8192;
        int bxi = local & 127, byi = local >> 7;       // old grid (128, 32)
        const float* src; short* dst; int cols, bxx;
        if (bxi < 96) { src = W_qkv; dst = Wqt; cols = 3072; bxx = bxi; }
        else          { src = W_proj; dst = Wpt; cols = 1024; bxx = bxi - 96; }
        int bx = bxx * 32, by = byi * 32;
        int tx = tid & 31, ty = tid >> 5;
        for (int j = 0; j < 4; ++j)
            tile[ty + j * 8][tx] = src[(size_t)(by + ty + j * 8) * cols + bx + tx];
        __syncthreads();
        for (int j = 0; j < 4; ++j)
            dst[(size_t)(bx + ty + j * 8) * 1024 + by + tx] = f2bf(tile[tx][ty + j * 8]);
        return;
    }
    int mblk = blk - 12288;                // ---- mask_flags (513 blocks)
    if (mblk == 512) {                     // fused pad_flags
        if (tid < 128) {
            int b = tid >> 5, kt = tid & 31;
            int any = 0;
            for (int j = 0; j < 64; ++j) any |= (padding[b * 2048 + kt * 64 + j] > 0);
            flags[512 + tid] = any;
        }
        return;
    }
    int qt = mblk >> 5, kt = mblk & 31;
    if (tid == 0) blockok = 1;
    __syncthreads();
    int ok = 1;
    for (int j = 0; j < 32; ++j) {
        int idx = j * 256 + tid;
        int qr = qt * 128 + (idx >> 6);
        int kc = kt * 64 + (idx & 63);
        ok &= (attn_mask[(size_t)qr * 2048 + kc] != 0);
    }
    if (!ok) blockok = 0;
    __syncthreads();
    if (tid == 0) flags[mblk] = blockok;
}

// ---------------------------------------------------------------------------
// R11/R12 (proven): 256x256x64 QKV GEMM, two-phase counted-vmcnt pipeline
// (T2+T3+T4+T5). 512 thr = 8 waves (2M x 4N), per-wave C = 128x64 (acc[8][4]).
// LDS = 2 dbuf x (A+B 256x64) = 128 KB -> 1 block/CU. vmcnt ledger: prologue
// 8; P1 issues 4, vmcnt(4) retires tile t's 8; P2 issues 4. Raw s_barrier
// only. NOTE: 2 blocks/CU is impossible at this tile (acc alone = 128 VGPR);
// the 384-block 1.5-pass tail is accepted — still beat 128² by ~10 us. LOCKED.
// ---------------------------------------------------------------------------
#define G256_STAGE(BUF, MAT, HALF, C, KT, SRC, BASE)                              \
    {                                                                             \
        int rr_ = (HALF) * 128 + (C) * 64 + w * 8 + l8;                           \
        async_cp16(&SRC[(size_t)((BASE) + rr_) * 1024 + (KT) * 64 +               \
                        ((j8 ^ (rr_ & 7)) << 3)],                                 \
                   &smem[BUF][MAT][(HALF) * 128 + (C) * 64 + w * 8][0]);          \
    }

__global__ __launch_bounds__(512, 2) void gemm256_qkv(
    const short* __restrict__ A, const short* __restrict__ Bt,
    short* __restrict__ q_ws, short* __restrict__ k_ws, short* __restrict__ v_ws) {
    __shared__ __align__(16) short smem[2][2][256][64];   // [buf][A/B][row][k] 128 KB

    int tid = threadIdx.x, lane = tid & 63, w = tid >> 6;   // 8 waves
    int wm = w & 1, wn = w >> 1;                            // 2M x 4N
    int col = lane & 15, quad = lane >> 4;
    int l8 = lane >> 3, j8 = lane & 7;

    // T1: XCD swizzle (384 blocks, %8==0 -> bijective)
    int nwg = gridDim.x * gridDim.y;
    int hw = blockIdx.y * gridDim.x + blockIdx.x;
    int logical = (hw & 7) * (nwg >> 3) + (hw >> 3);
    int bx = logical % gridDim.x, by = logical / gridDim.x;
    int m0 = by * 256, n0 = bx * 256;

    f32x4 acc[8][4] = {};

    // prologue: stage tile 0 into buf 0 (8 loads/thread-slice)
    G256_STAGE(0, 0, 0, 0, 0, A, m0) G256_STAGE(0, 0, 0, 1, 0, A, m0)
    G256_STAGE(0, 1, 0, 0, 0, Bt, n0) G256_STAGE(0, 1, 0, 1, 0, Bt, n0)
    G256_STAGE(0, 1, 1, 0, 0, Bt, n0) G256_STAGE(0, 1, 1, 1, 0, Bt, n0)
    G256_STAGE(0, 0, 1, 0, 0, A, m0) G256_STAGE(0, 0, 1, 1, 0, A, m0)

    for (int t = 0; t < 16; ++t) {
        int bt = t & 1, nb_ = bt ^ 1, ktn = t + 1;

        // ---- P1 ----
        if (t < 15) {
            G256_STAGE(nb_, 0, 0, 0, ktn, A, m0) G256_STAGE(nb_, 0, 0, 1, ktn, A, m0)
            G256_STAGE(nb_, 1, 0, 0, ktn, Bt, n0) G256_STAGE(nb_, 1, 0, 1, ktn, Bt, n0)
            asm volatile("s_waitcnt vmcnt(4)" ::: "memory");
        } else {
            asm volatile("s_waitcnt vmcnt(0)" ::: "memory");
        }
        __builtin_amdgcn_s_barrier();
        __builtin_amdgcn_sched_barrier(0);

        bf16x8 bfr[4][2], af[4][2];
        for (int nt = 0; nt < 4; ++nt)
            for (int ks = 0; ks < 2; ++ks)
                bfr[nt][ks] = *reinterpret_cast<const bf16x8*>(
                    &smem[bt][1][wn * 64 + nt * 16 + col][((ks * 4 + quad) ^ (col & 7)) << 3]);
        for (int mt = 0; mt < 4; ++mt)
            for (int ks = 0; ks < 2; ++ks)
                af[mt][ks] = *reinterpret_cast<const bf16x8*>(
                    &smem[bt][0][wm * 128 + mt * 16 + col][((ks * 4 + quad) ^ (col & 7)) << 3]);
        __builtin_amdgcn_s_setprio(1);
        for (int ks = 0; ks < 2; ++ks)
            for (int mt = 0; mt < 4; ++mt)
                for (int nt = 0; nt < 4; ++nt)
                    acc[mt][nt] = __builtin_amdgcn_mfma_f32_16x16x32_bf16(af[mt][ks], bfr[nt][ks], acc[mt][nt], 0, 0, 0);
        __builtin_amdgcn_s_setprio(0);

        // ---- P2 ----
        if (t < 15) {
            G256_STAGE(nb_, 1, 1, 0, ktn, Bt, n0) G256_STAGE(nb_, 1, 1, 1, ktn, Bt, n0)
            G256_STAGE(nb_, 0, 1, 0, ktn, A, m0) G256_STAGE(nb_, 0, 1, 1, ktn, A, m0)
        }
        for (int mt = 0; mt < 4; ++mt)
            for (int ks = 0; ks < 2; ++ks)
                af[mt][ks] = *reinterpret_cast<const bf16x8*>(
                    &smem[bt][0][wm * 128 + (4 + mt) * 16 + col][((ks * 4 + quad) ^ (col & 7)) << 3]);
        __builtin_amdgcn_s_setprio(1);
        for (int ks = 0; ks < 2; ++ks)
            for (int mt = 0; mt < 4; ++mt)
                for (int nt = 0; nt < 4; ++nt)
                    acc[4 + mt][nt] = __builtin_amdgcn_mfma_f32_16x16x32_bf16(af[mt][ks], bfr[nt][ks], acc[4 + mt][nt], 0, 0, 0);
        __builtin_amdgcn_s_setprio(0);
        __builtin_amdgcn_sched_barrier(0);
        __builtin_amdgcn_s_barrier();   // all reads retired (consumed) -> next stage safe
    }

    // epilogue: L = 256x256 bf16 view of the whole 128 KB smem.
    short* L = &smem[0][0][0][0];
    int which = n0 >> 10;                // 0=Q 1=K 2=V
    int cb = n0 & 1023;
    int b = m0 >> 11, nb = m0 & 2047, hb = cb >> 6;

    if (which == 2) {
        // V -> [bh][dd][n]: store transposed Lt[c][m], m-chunks rotated by c
        for (int mt = 0; mt < 8; ++mt)
            for (int nt = 0; nt < 4; ++nt) {
                int ml = wm * 128 + mt * 16 + quad * 4;
                int cl = wn * 64 + nt * 16 + col;
                int mp = (ml + 8 * cl) & 255;
                short4 pk;
                for (int r = 0; r < 4; ++r) ((short*)&pk)[r] = f2bf(acc[mt][nt][r]);
                *reinterpret_cast<short4*>(&L[cl * 256 + mp]) = pk;
            }
        __syncthreads();
        for (int it = 0; it < 16; ++it) {
            int chunk = it * 512 + tid;            // 256 c-rows x 32 chunks
            int c = chunk >> 5, j = chunk & 31;
            int h = hb + (c >> 6), dd = c & 63;
            int4 val = *reinterpret_cast<const int4*>(&L[c * 256 + (((j + c) & 31) << 3)]);
            *reinterpret_cast<int4*>(
                &v_ws[((size_t)((b * 16 + h) * 64 + dd)) * 2048 + nb + j * 8]) = val;
        }
    } else {
        short* dst = (which == 0) ? q_ws : k_ws;
        float scl = (which == 0) ? QSCALE : 1.0f;
        for (int mt = 0; mt < 8; ++mt)
            for (int nt = 0; nt < 4; ++nt)
                for (int r = 0; r < 4; ++r) {
                    int ml = wm * 128 + mt * 16 + quad * 4 + r;
                    int cl = wn * 64 + nt * 16 + col;
                    L[ml * 256 + ((cl + 8 * ml) & 255)] = f2bf(acc[mt][nt][r] * scl);
                }
        __syncthreads();
        for (int it = 0; it < 16; ++it) {
            int chunk = it * 512 + tid;            // 256 rows x 32 chunks
            int row = chunk >> 5, j = chunk & 31;
            int h = hb + (j >> 3), dd = (j & 7) * 8;
            int4 val = *reinterpret_cast<const int4*>(&L[row * 256 + (((j + row) & 31) << 3)]);
            *reinterpret_cast<int4*>(
                &dst[((size_t)(b * 16 + h) * 2048 + nb + row) * 64 + dd]) = val;
        }
    }
}

// ---------------------------------------------------------------------------
// proj GEMM: 128x128x64 m97 structure, 512 blocks = 2/CU (R13's 1/CU retile
// regressed; barrier phases need a co-resident block to interleave). LOCKED.
// ---------------------------------------------------------------------------
__global__ __launch_bounds__(256, 2) void gemm_bf16(
    const short* __restrict__ A, const short* __restrict__ Bt, int mode,
    short* __restrict__ q_ws, short* __restrict__ k_ws, short* __restrict__ v_ws,
    float* __restrict__ out, const float* __restrict__ bias) {
    const int K = 1024;
    __shared__ __align__(16) short smem[2][128][64];   // As/Bs, reused by epilogue
    short (*As)[64] = smem[0];
    short (*Bs)[64] = smem[1];
    int tid = threadIdx.x, lane = tid & 63, w = tid >> 6;
    int wm = w & 1, wn = w >> 1;

    int nwg = gridDim.x * gridDim.y;
    int hw = blockIdx.y * gridDim.x + blockIdx.x;
    int logical = (hw & 7) * (nwg >> 3) + (hw >> 3);
    int bx = logical % gridDim.x, by = logical / gridDim.x;
    int m0 = by * 128, n0 = bx * 128;

    int col = lane & 15, quad = lane >> 4;
    int l8 = lane >> 3, j8 = lane & 7;

    f32x4 acc[4][4] = {};

    for (int k0 = 0; k0 < K; k0 += 64) {
        for (int c = 0; c < 4; ++c) {
            int rr = w * 32 + c * 8 + l8;
            int sw = (j8 ^ (rr & 7)) << 3;
            async_cp16(&A[(size_t)(m0 + rr) * K + k0 + sw], &As[w * 32 + c * 8][0]);
            async_cp16(&Bt[(size_t)(n0 + rr) * K + k0 + sw], &Bs[w * 32 + c * 8][0]);
        }
        __syncthreads();
        for (int ks = 0; ks < 2; ++ks) {
            bf16x8 af[4], bfr[4];
            for (int mt = 0; mt < 4; ++mt)
                af[mt] = *reinterpret_cast<const bf16x8*>(
                    &As[wm * 64 + mt * 16 + col][((ks * 4 + quad) ^ (col & 7)) << 3]);
            for (int nt = 0; nt < 4; ++nt)
                bfr[nt] = *reinterpret_cast<const bf16x8*>(
                    &Bs[wn * 64 + nt * 16 + col][((ks * 4 + quad) ^ (col & 7)) << 3]);
            for (int mt = 0; mt < 4; ++mt)
                for (int nt = 0; nt < 4; ++nt)
                    acc[mt][nt] = __builtin_amdgcn_mfma_f32_16x16x32_bf16(af[mt], bfr[nt], acc[mt][nt], 0, 0, 0);
        }
        __syncthreads();
    }

    short* L = &smem[0][0][0];   // 128x128 bf16 view (32 KB)

    if (mode == 0) {
        int which = n0 >> 10;
        int cb = n0 & 1023;
        int b = m0 >> 11, nb = m0 & 2047, hb = cb >> 6;
        if (which == 2) {
            for (int mt = 0; mt < 4; ++mt)
                for (int nt = 0; nt < 4; ++nt) {
                    int ml = wm * 64 + mt * 16 + quad * 4;
                    int cl = wn * 64 + nt * 16 + col;
                    int mp = (ml + 8 * cl) & 127;
                    short4 pk;
                    for (int r = 0; r < 4; ++r) ((short*)&pk)[r] = f2bf(acc[mt][nt][r]);
                    *reinterpret_cast<short4*>(&L[cl * 128 + mp]) = pk;
                }
            __syncthreads();
            for (int it = 0; it < 8; ++it) {
                int chunk = it * 256 + tid;
                int c = chunk >> 4, j = chunk & 15;
                int h = hb + (c >> 6), dd = c & 63;
                int4 val = *reinterpret_cast<const int4*>(&L[c * 128 + (((j + c) & 15) << 3)]);
                *reinterpret_cast<int4*>(
                    &v_ws[((size_t)((b * 16 + h) * 64 + dd)) * 2048 + nb + j * 8]) = val;
            }
        } else {
            short* dst = (which == 0) ? q_ws : k_ws;
            float scl = (which == 0) ? QSCALE : 1.0f;
            for (int mt = 0; mt < 4; ++mt)
                for (int nt = 0; nt < 4; ++nt)
                    for (int r = 0; r < 4; ++r) {
                        int ml = wm * 64 + mt * 16 + quad * 4 + r;
                        int cl = wn * 64 + nt * 16 + col;
                        L[ml * 128 + ((cl + 8 * ml) & 127)] = f2bf(acc[mt][nt][r] * scl);
                    }
            __syncthreads();
            for (int it = 0; it < 8; ++it) {
                int chunk = it * 256 + tid;
                int row = chunk >> 4, j = chunk & 15;
                int h = hb + (j >> 3), dd = (j & 7) * 8;
                int4 val = *reinterpret_cast<const int4*>(&L[row * 128 + (((j + row) & 15) << 3)]);
                *reinterpret_cast<int4*>(
                    &dst[((size_t)(b * 16 + h) * 2048 + nb + row) * 64 + dd]) = val;
            }
        }
    } else {
        float* Lf = reinterpret_cast<float*>(L);       // 64 x 128 fp32
        for (int half = 0; half < 2; ++half) {
            if (wm == half) {
                for (int mt = 0; mt < 4; ++mt)
                    for (int nt = 0; nt < 4; ++nt)
                        for (int r = 0; r < 4; ++r) {
                            int ml = mt * 16 + quad * 4 + r;
                            int cl = wn * 64 + nt * 16 + col;
                            Lf[ml * 128 + cl] = acc[mt][nt][r];
                        }
            }
            __syncthreads();
            for (int it = 0; it < 8; ++it) {
                int chunk = it * 256 + tid;
                int row = chunk >> 5, j = chunk & 31;
                float4 val = *reinterpret_cast<const float4*>(&Lf[row * 128 + j * 4]);
                float4 bv = *reinterpret_cast<const float4*>(&bias[n0 + j * 4]);
                val.x += bv.x; val.y += bv.y; val.z += bv.z; val.w += bv.w;
                *reinterpret_cast<float4*>(
                    &out[(size_t)(m0 + half * 64 + row) * 1024 + n0 + j * 4]) = val;
            }
            __syncthreads();
        }
    }
}

// ---------------------------------------------------------------------------
// Flash attention, R15: R6's locked structure (4 waves x 32 qrows, 16x16
// MFMA, P-via-LDS, single K buffer, 2 barriers/iter, XCD swizzle) + the two
// components never isolated on it: ballot-prefolded flags (removes 2 uniform
// loads/iter) and s_setprio(1) around MFMA bursts only (T5: +4-7% attn,
// m191; NULL only on barrier-lockstep GEMMs, m190). No barrier/LDS/staging/
// register changes — structure remains frozen per the R5-R10 ledger.
// ---------------------------------------------------------------------------
__global__ __launch_bounds__(256, 4) void flash_attn(
    const short* __restrict__ q_ws, const short* __restrict__ k_ws,
    const short* __restrict__ v_ws, const int* __restrict__ aflags,
    const int* __restrict__ pflags, const int* __restrict__ padding,
    const int* __restrict__ attn_mask, short* __restrict__ xb) {
    const int Nn = 2048, D = 64;
    __shared__ short QP[128][64];   // Q staging, then P tile (both wave-private rows)
    __shared__ short Ks[64][64];
    __shared__ short Vt[64][64];    // V^T: [d][kcol]
    __shared__ __align__(16) float padb[64];

    int tid = threadIdx.x, lane = tid & 63, w = tid >> 6;
    int col = lane & 15, quad = lane >> 4;

    int hw = blockIdx.y * 16 + blockIdx.x;
    int logical = (hw & 7) * 128 + (hw >> 3);
    int bh = logical >> 4, qt = logical & 15;
    int b = bh >> 4, h = bh & 15;
    int q0 = qt * 128;

    int l8 = lane >> 3, j8 = lane & 7;

    // ballot-prefold flags into bitmasks (bit kt): no flag loads in the loop
    unsigned amask = (unsigned)__ballot(aflags[qt * 32 + (lane & 31)] != 0);
    unsigned pmask = (unsigned)__ballot(pflags[b * 32 + (lane & 31)] != 0);

    for (int c = 0; c < 4; ++c) {
        int rr = w * 32 + c * 8 + l8;
        async_cp16(&q_ws[((size_t)bh * Nn + q0 + rr) * D + ((j8 ^ (rr & 7)) << 3)],
                   &QP[w * 32 + c * 8][0]);
    }
    __syncthreads();

    bf16x8 qf[2][2];
    for (int t = 0; t < 2; ++t)
        for (int ks = 0; ks < 2; ++ks)
            qf[t][ks] = *reinterpret_cast<const bf16x8*>(
                &QP[w * 32 + t * 16 + col][((ks * 4 + quad) ^ (col & 7)) << 3]);

    f32x4 oacc[2][4] = {};
    f32x4 lacc[2] = {};

    for (int kt = 0; kt < 32; ++kt) {
        int k0 = kt * 64;
        for (int c = 0; c < 2; ++c) {
            int rr = w * 16 + c * 8 + l8;
            int sw = (j8 ^ (rr & 7)) << 3;
            async_cp16(&k_ws[((size_t)bh * Nn + k0 + rr) * D + sw], &Ks[w * 16 + c * 8][0]);
            async_cp16(&v_ws[((size_t)bh * D + rr) * Nn + k0 + sw], &Vt[w * 16 + c * 8][0]);
        }
        int pflag = (pmask >> kt) & 1;
        if (pflag && tid < 64) padb[tid] = (padding[b * Nn + k0 + tid] > 0) ? NEG : 0.f;
        __syncthreads();

        f32x4 sacc[4][2] = {};
        for (int ks = 0; ks < 2; ++ks) {
            bf16x8 kf[4];
            for (int mt = 0; mt < 4; ++mt)
                kf[mt] = *reinterpret_cast<const bf16x8*>(
                    &Ks[mt * 16 + col][((ks * 4 + quad) ^ (col & 7)) << 3]);
            __builtin_amdgcn_s_setprio(1);
            for (int mt = 0; mt < 4; ++mt)
                for (int t = 0; t < 2; ++t)
                    sacc[mt][t] = __builtin_amdgcn_mfma_f32_16x16x32_bf16(kf[mt], qf[t][ks], sacc[mt][t], 0, 0, 0);
            __builtin_amdgcn_s_setprio(0);
        }

        if (!((amask >> kt) & 1)) {
            for (int mt = 0; mt < 4; ++mt)
                for (int t = 0; t < 2; ++t)
                    for (int r = 0; r < 4; ++r) {
                        int kc = k0 + mt * 16 + quad * 4 + r;
                        int qr = q0 + w * 32 + t * 16 + col;
                        if (attn_mask[(size_t)qr * Nn + kc] == 0) sacc[mt][t][r] = NEG;
                    }
        }
        if (pflag) {
            for (int mt = 0; mt < 4; ++mt) {
                f32x4 pb = *reinterpret_cast<const f32x4*>(&padb[mt * 16 + quad * 4]);
                for (int t = 0; t < 2; ++t)
                    for (int r = 0; r < 4; ++r) sacc[mt][t][r] += pb[r];
            }
        }

        for (int t = 0; t < 2; ++t) {
            int qrow = w * 32 + t * 16 + col;
            for (int mt = 0; mt < 4; ++mt) {
                f32x4 e;
                e[0] = __builtin_amdgcn_exp2f(sacc[mt][t][0]);
                e[1] = __builtin_amdgcn_exp2f(sacc[mt][t][1]);
                e[2] = __builtin_amdgcn_exp2f(sacc[mt][t][2]);
                e[3] = __builtin_amdgcn_exp2f(sacc[mt][t][3]);
                lacc[t] += e;
                unsigned p0 = pack_bf16_2(e[0], e[1]);
                unsigned p1 = pack_bf16_2(e[2], e[3]);
                int chunk = (mt * 2 + (quad >> 1)) ^ (col & 7);
                *reinterpret_cast<uint2*>(&QP[qrow][(chunk << 3) + ((quad & 1) << 2)]) =
                    make_uint2(p0, p1);
            }
        }

        for (int ks = 0; ks < 2; ++ks) {
            bf16x8 pf[2], vf[4];
            for (int t = 0; t < 2; ++t)
                pf[t] = *reinterpret_cast<const bf16x8*>(
                    &QP[w * 32 + t * 16 + col][((ks * 4 + quad) ^ (col & 7)) << 3]);
            for (int nt = 0; nt < 4; ++nt)
                vf[nt] = *reinterpret_cast<const bf16x8*>(
                    &Vt[nt * 16 + col][((ks * 4 + quad) ^ (col & 7)) << 3]);
            __builtin_amdgcn_s_setprio(1);
            for (int t = 0; t < 2; ++t)
                for (int nt = 0; nt < 4; ++nt)
                    oacc[t][nt] = __builtin_amdgcn_mfma_f32_16x16x32_bf16(pf[t], vf[nt], oacc[t][nt], 0, 0, 0);
            __builtin_amdgcn_s_setprio(0);
        }
        __syncthreads();
    }

    for (int t = 0; t < 2; ++t) {
        float ls = lacc[t][0] + lacc[t][1] + lacc[t][2] + lacc[t][3];
        ls += __shfl_xor(ls, 16);
        ls += __shfl_xor(ls, 32);
        for (int r = 0; r < 4; ++r) {
            float lv = __shfl(ls, quad * 4 + r, 16);
            float inv = 1.f / lv;
            int n = q0 + w * 32 + t * 16 + quad * 4 + r;
            for (int nt = 0; nt < 4; ++nt) {
                int dd = nt * 16 + col;
                xb[((size_t)(b * Nn + n)) * 1024 + h * 64 + dd] = f2bf(oacc[t][nt][r] * inv);
            }
        }
    }
}

// ---------------------------------------------------------------------------
extern "C" void kernel_launch(void* const* d_in, const int* in_sizes, int n_in,
                              void* d_out, int out_size, void* d_ws, size_t ws_size,
                              hipStream_t stream) {
    const float* x        = (const float*)d_in[0];   // (4,2048,1024) fp32
    const int* attn_mask  = (const int*)d_in[1];     // (2048,2048)
    const int* padding    = (const int*)d_in[2];     // (4,2048)
    const float* W_qkv    = (const float*)d_in[3];   // (1024,3072)
    const float* W_proj   = (const float*)d_in[4];   // (1024,1024)
    const float* b_proj   = (const float*)d_in[5];   // (1024,)
    float* out            = (float*)d_out;

    char* ws = (char*)d_ws;
    short* Xb   = (short*)(ws);                 // 16 MB  (8192x1024 bf16)
    short* Wqt  = (short*)(ws + (16u << 20));   // 6 MB   (3072x1024 bf16, W_qkv^T)
    short* Wpt  = (short*)(ws + (22u << 20));   // 2 MB   (1024x1024 bf16, W_proj^T)
    short* q_ws = (short*)(ws + (24u << 20));   // 16 MB  (64,2048,64) pre-scaled (exp2 dom.)
    short* k_ws = (short*)(ws + (40u << 20));   // 16 MB  (64,2048,64)
    short* v_ws = (short*)(ws + (56u << 20));   // 16 MB  (64,64,2048) transposed
    short* xbuf = (short*)(ws + (72u << 20));   // 16 MB  (8192x1024 bf16) attn out
    int*  flags = (int*)(ws + (88u << 20));     // attn flags [512] + pad flags [128]

    prep_fused<<<12801, 256, 0, stream>>>(x, Xb, W_qkv, Wqt, W_proj, Wpt,
                                          attn_mask, padding, flags);

    gemm256_qkv<<<dim3(3072 / 256, 8192 / 256), 512, 0, stream>>>(
        Xb, Wqt, q_ws, k_ws, v_ws);

    flash_attn<<<dim3(16, 64), 256, 0, stream>>>(
        q_ws, k_ws, v_ws, flags, flags + 512, padding, attn_mask, xbuf);

    gemm_bf16<<<dim3(1024 / 128, 8192 / 128), 256, 0, stream>>>(
        xbuf, Wpt, 1, nullptr, nullptr, nullptr, out, b_proj);
}

// Round 12
// 281.607 us; speedup vs baseline: 1.1683x; 1.1683x over previous
//
#include <hip/hip_runtime.h>

#define NEG -10000000.0f
#define QSCALE 0.18033688011112042f   // 0.125 (d^-0.5) * log2(e): softmax in exp2 domain

typedef __attribute__((ext_vector_type(8))) short bf16x8;
typedef __attribute__((ext_vector_type(4))) float f32x4;

static __device__ __forceinline__ short f2bf(float f) {
    unsigned int u = __float_as_uint(f);
    unsigned int r = (u + 0x7fffu + ((u >> 16) & 1u)) >> 16;
    return (short)r;
}

// pack two fp32 -> packed bf16x2 (round-half-up; exp outputs, ties measure-zero)
static __device__ __forceinline__ unsigned pack_bf16_2(float a, float b) {
    unsigned ua = __float_as_uint(a) + 0x8000u;
    unsigned ub = __float_as_uint(b) + 0x8000u;
    return __builtin_amdgcn_perm(ub, ua, 0x07060302u);
}

// async global->LDS, 16B per lane. lds base wave-uniform; lane i lands at +16*i.
static __device__ __forceinline__ void async_cp16(const void* g, void* l) {
    __builtin_amdgcn_global_load_lds(
        (const __attribute__((address_space(1))) unsigned int*)g,
        (__attribute__((address_space(3))) unsigned int*)l, 16, 0, 0);
}

// ---------------------------------------------------------------------------
// R14: all prep work in ONE launch (was 3): removes 2 inter-dispatch gaps.
// Block ranges (block-uniform branches, bodies identical to proven kernels):
//   [0,8192)       cvt_bf16 of x -> Xb
//   [8192,12288)   transpose_cvt of W_qkv->Wqt (first 96 cols-tiles) / W_proj->Wpt
//   [12288,12801)  mask_flags + fused pad_flags (block 512)
// ---------------------------------------------------------------------------
__global__ void prep_fused(const float* __restrict__ x, short* __restrict__ Xb,
                           const float* __restrict__ W_qkv, short* __restrict__ Wqt,
                           const float* __restrict__ W_proj, short* __restrict__ Wpt,
                           const int* __restrict__ attn_mask,
                           const int* __restrict__ padding, int* __restrict__ flags) {
    __shared__ float tile[32][33];
    __shared__ int blockok;
    int blk = blockIdx.x, tid = threadIdx.x;

    if (blk < 8192) {                      // ---- cvt_bf16 (n4 = 2097152 exact)
        int i = blk * 256 + tid;
        float4 v = reinterpret_cast<const float4*>(x)[i];
        short4 o;
        o.x = f2bf(v.x); o.y = f2bf(v.y); o.z = f2bf(v.z); o.w = f2bf(v.w);
        reinterpret_cast<short4*>(Xb)[i] = o;
        return;
    }
    if (blk < 12288) {                     // ---- weight transposes (4096 blocks)
        int local = blk - 8192;
        int bxi = local & 127, byi = local >> 7;       // old grid (128, 32)
        const float* src; short* dst; int cols, bxx;
        if (bxi < 96) { src = W_qkv; dst = Wqt; cols = 3072; bxx = bxi; }
        else          { src = W_proj; dst = Wpt; cols = 1024; bxx = bxi - 96; }
        int bx = bxx * 32, by = byi * 32;
        int tx = tid & 31, ty = tid >> 5;
        for (int j = 0; j < 4; ++j)
            tile[ty + j * 8][tx] = src[(size_t)(by + ty + j * 8) * cols + bx + tx];
        __syncthreads();
        for (int j = 0; j < 4; ++j)
            dst[(size_t)(bx + ty + j * 8) * 1024 + by + tx] = f2bf(tile[tx][ty + j * 8]);
        return;
    }
    int mblk = blk - 12288;                // ---- mask_flags (513 blocks)
    if (mblk == 512) {                     // fused pad_flags
        if (tid < 128) {
            int b = tid >> 5, kt = tid & 31;
            int any = 0;
            for (int j = 0; j < 64; ++j) any |= (padding[b * 2048 + kt * 64 + j] > 0);
            flags[512 + tid] = any;
        }
        return;
    }
    int qt = mblk >> 5, kt = mblk & 31;
    if (tid == 0) blockok = 1;
    __syncthreads();
    int ok = 1;
    for (int j = 0; j < 32; ++j) {
        int idx = j * 256 + tid;
        int qr = qt * 128 + (idx >> 6);
        int kc = kt * 64 + (idx & 63);
        ok &= (attn_mask[(size_t)qr * 2048 + kc] != 0);
    }
    if (!ok) blockok = 0;
    __syncthreads();
    if (tid == 0) flags[mblk] = blockok;
}

// ---------------------------------------------------------------------------
// R11/R12 (proven): 256x256x64 QKV GEMM, two-phase counted-vmcnt pipeline
// (T2+T3+T4+T5). 512 thr = 8 waves (2M x 4N), per-wave C = 128x64 (acc[8][4]).
// LDS = 2 dbuf x (A+B 256x64) = 128 KB -> 1 block/CU. vmcnt ledger: prologue
// 8; P1 issues 4, vmcnt(4) retires tile t's 8; P2 issues 4. Raw s_barrier
// only. LOCKED.
// ---------------------------------------------------------------------------
#define G256_STAGE(BUF, MAT, HALF, C, KT, SRC, BASE)                              \
    {                                                                             \
        int rr_ = (HALF) * 128 + (C) * 64 + w * 8 + l8;                           \
        async_cp16(&SRC[(size_t)((BASE) + rr_) * 1024 + (KT) * 64 +               \
                        ((j8 ^ (rr_ & 7)) << 3)],                                 \
                   &smem[BUF][MAT][(HALF) * 128 + (C) * 64 + w * 8][0]);          \
    }

__global__ __launch_bounds__(512, 2) void gemm256_qkv(
    const short* __restrict__ A, const short* __restrict__ Bt,
    short* __restrict__ q_ws, short* __restrict__ k_ws, short* __restrict__ v_ws) {
    __shared__ __align__(16) short smem[2][2][256][64];   // [buf][A/B][row][k] 128 KB

    int tid = threadIdx.x, lane = tid & 63, w = tid >> 6;   // 8 waves
    int wm = w & 1, wn = w >> 1;                            // 2M x 4N
    int col = lane & 15, quad = lane >> 4;
    int l8 = lane >> 3, j8 = lane & 7;

    // T1: XCD swizzle (384 blocks, %8==0 -> bijective)
    int nwg = gridDim.x * gridDim.y;
    int hw = blockIdx.y * gridDim.x + blockIdx.x;
    int logical = (hw & 7) * (nwg >> 3) + (hw >> 3);
    int bx = logical % gridDim.x, by = logical / gridDim.x;
    int m0 = by * 256, n0 = bx * 256;

    f32x4 acc[8][4] = {};

    // prologue: stage tile 0 into buf 0 (8 loads/thread-slice)
    G256_STAGE(0, 0, 0, 0, 0, A, m0) G256_STAGE(0, 0, 0, 1, 0, A, m0)
    G256_STAGE(0, 1, 0, 0, 0, Bt, n0) G256_STAGE(0, 1, 0, 1, 0, Bt, n0)
    G256_STAGE(0, 1, 1, 0, 0, Bt, n0) G256_STAGE(0, 1, 1, 1, 0, Bt, n0)
    G256_STAGE(0, 0, 1, 0, 0, A, m0) G256_STAGE(0, 0, 1, 1, 0, A, m0)

    for (int t = 0; t < 16; ++t) {
        int bt = t & 1, nb_ = bt ^ 1, ktn = t + 1;

        // ---- P1 ----
        if (t < 15) {
            G256_STAGE(nb_, 0, 0, 0, ktn, A, m0) G256_STAGE(nb_, 0, 0, 1, ktn, A, m0)
            G256_STAGE(nb_, 1, 0, 0, ktn, Bt, n0) G256_STAGE(nb_, 1, 0, 1, ktn, Bt, n0)
            asm volatile("s_waitcnt vmcnt(4)" ::: "memory");
        } else {
            asm volatile("s_waitcnt vmcnt(0)" ::: "memory");
        }
        __builtin_amdgcn_s_barrier();
        __builtin_amdgcn_sched_barrier(0);

        bf16x8 bfr[4][2], af[4][2];
        for (int nt = 0; nt < 4; ++nt)
            for (int ks = 0; ks < 2; ++ks)
                bfr[nt][ks] = *reinterpret_cast<const bf16x8*>(
                    &smem[bt][1][wn * 64 + nt * 16 + col][((ks * 4 + quad) ^ (col & 7)) << 3]);
        for (int mt = 0; mt < 4; ++mt)
            for (int ks = 0; ks < 2; ++ks)
                af[mt][ks] = *reinterpret_cast<const bf16x8*>(
                    &smem[bt][0][wm * 128 + mt * 16 + col][((ks * 4 + quad) ^ (col & 7)) << 3]);
        __builtin_amdgcn_s_setprio(1);
        for (int ks = 0; ks < 2; ++ks)
            for (int mt = 0; mt < 4; ++mt)
                for (int nt = 0; nt < 4; ++nt)
                    acc[mt][nt] = __builtin_amdgcn_mfma_f32_16x16x32_bf16(af[mt][ks], bfr[nt][ks], acc[mt][nt], 0, 0, 0);
        __builtin_amdgcn_s_setprio(0);

        // ---- P2 ----
        if (t < 15) {
            G256_STAGE(nb_, 1, 1, 0, ktn, Bt, n0) G256_STAGE(nb_, 1, 1, 1, ktn, Bt, n0)
            G256_STAGE(nb_, 0, 1, 0, ktn, A, m0) G256_STAGE(nb_, 0, 1, 1, ktn, A, m0)
        }
        for (int mt = 0; mt < 4; ++mt)
            for (int ks = 0; ks < 2; ++ks)
                af[mt][ks] = *reinterpret_cast<const bf16x8*>(
                    &smem[bt][0][wm * 128 + (4 + mt) * 16 + col][((ks * 4 + quad) ^ (col & 7)) << 3]);
        __builtin_amdgcn_s_setprio(1);
        for (int ks = 0; ks < 2; ++ks)
            for (int mt = 0; mt < 4; ++mt)
                for (int nt = 0; nt < 4; ++nt)
                    acc[4 + mt][nt] = __builtin_amdgcn_mfma_f32_16x16x32_bf16(af[mt][ks], bfr[nt][ks], acc[4 + mt][nt], 0, 0, 0);
        __builtin_amdgcn_s_setprio(0);
        __builtin_amdgcn_sched_barrier(0);
        __builtin_amdgcn_s_barrier();   // all reads retired (consumed) -> next stage safe
    }

    // epilogue: L = 256x256 bf16 view of the whole 128 KB smem.
    short* L = &smem[0][0][0][0];
    int which = n0 >> 10;                // 0=Q 1=K 2=V
    int cb = n0 & 1023;
    int b = m0 >> 11, nb = m0 & 2047, hb = cb >> 6;

    if (which == 2) {
        // V -> [bh][dd][n]: store transposed Lt[c][m], m-chunks rotated by c
        for (int mt = 0; mt < 8; ++mt)
            for (int nt = 0; nt < 4; ++nt) {
                int ml = wm * 128 + mt * 16 + quad * 4;
                int cl = wn * 64 + nt * 16 + col;
                int mp = (ml + 8 * cl) & 255;
                short4 pk;
                for (int r = 0; r < 4; ++r) ((short*)&pk)[r] = f2bf(acc[mt][nt][r]);
                *reinterpret_cast<short4*>(&L[cl * 256 + mp]) = pk;
            }
        __syncthreads();
        for (int it = 0; it < 16; ++it) {
            int chunk = it * 512 + tid;            // 256 c-rows x 32 chunks
            int c = chunk >> 5, j = chunk & 31;
            int h = hb + (c >> 6), dd = c & 63;
            int4 val = *reinterpret_cast<const int4*>(&L[c * 256 + (((j + c) & 31) << 3)]);
            *reinterpret_cast<int4*>(
                &v_ws[((size_t)((b * 16 + h) * 64 + dd)) * 2048 + nb + j * 8]) = val;
        }
    } else {
        short* dst = (which == 0) ? q_ws : k_ws;
        float scl = (which == 0) ? QSCALE : 1.0f;
        for (int mt = 0; mt < 8; ++mt)
            for (int nt = 0; nt < 4; ++nt)
                for (int r = 0; r < 4; ++r) {
                    int ml = wm * 128 + mt * 16 + quad * 4 + r;
                    int cl = wn * 64 + nt * 16 + col;
                    L[ml * 256 + ((cl + 8 * ml) & 255)] = f2bf(acc[mt][nt][r] * scl);
                }
        __syncthreads();
        for (int it = 0; it < 16; ++it) {
            int chunk = it * 512 + tid;            // 256 rows x 32 chunks
            int row = chunk >> 5, j = chunk & 31;
            int h = hb + (j >> 3), dd = (j & 7) * 8;
            int4 val = *reinterpret_cast<const int4*>(&L[row * 256 + (((j + row) & 31) << 3)]);
            *reinterpret_cast<int4*>(
                &dst[((size_t)(b * 16 + h) * 2048 + nb + row) * 64 + dd]) = val;
        }
    }
}

// ---------------------------------------------------------------------------
// proj GEMM: 128x128x64 m97 structure, 512 blocks = 2/CU (R13's 1/CU retile
// regressed; barrier phases need a co-resident block to interleave). LOCKED.
// ---------------------------------------------------------------------------
__global__ __launch_bounds__(256, 2) void gemm_bf16(
    const short* __restrict__ A, const short* __restrict__ Bt, int mode,
    short* __restrict__ q_ws, short* __restrict__ k_ws, short* __restrict__ v_ws,
    float* __restrict__ out, const float* __restrict__ bias) {
    const int K = 1024;
    __shared__ __align__(16) short smem[2][128][64];   // As/Bs, reused by epilogue
    short (*As)[64] = smem[0];
    short (*Bs)[64] = smem[1];
    int tid = threadIdx.x, lane = tid & 63, w = tid >> 6;
    int wm = w & 1, wn = w >> 1;

    int nwg = gridDim.x * gridDim.y;
    int hw = blockIdx.y * gridDim.x + blockIdx.x;
    int logical = (hw & 7) * (nwg >> 3) + (hw >> 3);
    int bx = logical % gridDim.x, by = logical / gridDim.x;
    int m0 = by * 128, n0 = bx * 128;

    int col = lane & 15, quad = lane >> 4;
    int l8 = lane >> 3, j8 = lane & 7;

    f32x4 acc[4][4] = {};

    for (int k0 = 0; k0 < K; k0 += 64) {
        for (int c = 0; c < 4; ++c) {
            int rr = w * 32 + c * 8 + l8;
            int sw = (j8 ^ (rr & 7)) << 3;
            async_cp16(&A[(size_t)(m0 + rr) * K + k0 + sw], &As[w * 32 + c * 8][0]);
            async_cp16(&Bt[(size_t)(n0 + rr) * K + k0 + sw], &Bs[w * 32 + c * 8][0]);
        }
        __syncthreads();
        for (int ks = 0; ks < 2; ++ks) {
            bf16x8 af[4], bfr[4];
            for (int mt = 0; mt < 4; ++mt)
                af[mt] = *reinterpret_cast<const bf16x8*>(
                    &As[wm * 64 + mt * 16 + col][((ks * 4 + quad) ^ (col & 7)) << 3]);
            for (int nt = 0; nt < 4; ++nt)
                bfr[nt] = *reinterpret_cast<const bf16x8*>(
                    &Bs[wn * 64 + nt * 16 + col][((ks * 4 + quad) ^ (col & 7)) << 3]);
            for (int mt = 0; mt < 4; ++mt)
                for (int nt = 0; nt < 4; ++nt)
                    acc[mt][nt] = __builtin_amdgcn_mfma_f32_16x16x32_bf16(af[mt], bfr[nt], acc[mt][nt], 0, 0, 0);
        }
        __syncthreads();
    }

    short* L = &smem[0][0][0];   // 128x128 bf16 view (32 KB)

    if (mode == 0) {
        int which = n0 >> 10;
        int cb = n0 & 1023;
        int b = m0 >> 11, nb = m0 & 2047, hb = cb >> 6;
        if (which == 2) {
            for (int mt = 0; mt < 4; ++mt)
                for (int nt = 0; nt < 4; ++nt) {
                    int ml = wm * 64 + mt * 16 + quad * 4;
                    int cl = wn * 64 + nt * 16 + col;
                    int mp = (ml + 8 * cl) & 127;
                    short4 pk;
                    for (int r = 0; r < 4; ++r) ((short*)&pk)[r] = f2bf(acc[mt][nt][r]);
                    *reinterpret_cast<short4*>(&L[cl * 128 + mp]) = pk;
                }
            __syncthreads();
            for (int it = 0; it < 8; ++it) {
                int chunk = it * 256 + tid;
                int c = chunk >> 4, j = chunk & 15;
                int h = hb + (c >> 6), dd = c & 63;
                int4 val = *reinterpret_cast<const int4*>(&L[c * 128 + (((j + c) & 15) << 3)]);
                *reinterpret_cast<int4*>(
                    &v_ws[((size_t)((b * 16 + h) * 64 + dd)) * 2048 + nb + j * 8]) = val;
            }
        } else {
            short* dst = (which == 0) ? q_ws : k_ws;
            float scl = (which == 0) ? QSCALE : 1.0f;
            for (int mt = 0; mt < 4; ++mt)
                for (int nt = 0; nt < 4; ++nt)
                    for (int r = 0; r < 4; ++r) {
                        int ml = wm * 64 + mt * 16 + quad * 4 + r;
                        int cl = wn * 64 + nt * 16 + col;
                        L[ml * 128 + ((cl + 8 * ml) & 127)] = f2bf(acc[mt][nt][r] * scl);
                    }
            __syncthreads();
            for (int it = 0; it < 8; ++it) {
                int chunk = it * 256 + tid;
                int row = chunk >> 4, j = chunk & 15;
                int h = hb + (j >> 3), dd = (j & 7) * 8;
                int4 val = *reinterpret_cast<const int4*>(&L[row * 128 + (((j + row) & 15) << 3)]);
                *reinterpret_cast<int4*>(
                    &dst[((size_t)(b * 16 + h) * 2048 + nb + row) * 64 + dd]) = val;
            }
        }
    } else {
        float* Lf = reinterpret_cast<float*>(L);       // 64 x 128 fp32
        for (int half = 0; half < 2; ++half) {
            if (wm == half) {
                for (int mt = 0; mt < 4; ++mt)
                    for (int nt = 0; nt < 4; ++nt)
                        for (int r = 0; r < 4; ++r) {
                            int ml = mt * 16 + quad * 4 + r;
                            int cl = wn * 64 + nt * 16 + col;
                            Lf[ml * 128 + cl] = acc[mt][nt][r];
                        }
            }
            __syncthreads();
            for (int it = 0; it < 8; ++it) {
                int chunk = it * 256 + tid;
                int row = chunk >> 5, j = chunk & 31;
                float4 val = *reinterpret_cast<const float4*>(&Lf[row * 128 + j * 4]);
                float4 bv = *reinterpret_cast<const float4*>(&bias[n0 + j * 4]);
                val.x += bv.x; val.y += bv.y; val.z += bv.z; val.w += bv.w;
                *reinterpret_cast<float4*>(
                    &out[(size_t)(m0 + half * 64 + row) * 1024 + n0 + j * 4]) = val;
            }
            __syncthreads();
        }
    }
}

// ---------------------------------------------------------------------------
// Flash attention: EXACT R6 restore — 4 waves x 32 qrows, 16x16 MFMA,
// P-via-LDS, single K buffer, 2 barriers/iter, XCD swizzle. Seven variants
// (R5,R7,R8,R9,R10,R15-ballot,R15-setprio) all regressed 20-55%: this kernel
// is the empirical optimum of its structure family. FROZEN — byte-identical
// to the R12/R14 binaries that measured 97.7-99.5 us.
// ---------------------------------------------------------------------------
__global__ __launch_bounds__(256, 4) void flash_attn(
    const short* __restrict__ q_ws, const short* __restrict__ k_ws,
    const short* __restrict__ v_ws, const int* __restrict__ aflags,
    const int* __restrict__ pflags, const int* __restrict__ padding,
    const int* __restrict__ attn_mask, short* __restrict__ xb) {
    const int Nn = 2048, D = 64;
    __shared__ short QP[128][64];   // Q staging, then P tile (both wave-private rows)
    __shared__ short Ks[64][64];
    __shared__ short Vt[64][64];    // V^T: [d][kcol]
    __shared__ __align__(16) float padb[64];

    int tid = threadIdx.x, lane = tid & 63, w = tid >> 6;
    int col = lane & 15, quad = lane >> 4;

    int hw = blockIdx.y * 16 + blockIdx.x;
    int logical = (hw & 7) * 128 + (hw >> 3);
    int bh = logical >> 4, qt = logical & 15;
    int b = bh >> 4, h = bh & 15;
    int q0 = qt * 128;

    int l8 = lane >> 3, j8 = lane & 7;

    for (int c = 0; c < 4; ++c) {
        int rr = w * 32 + c * 8 + l8;
        async_cp16(&q_ws[((size_t)bh * Nn + q0 + rr) * D + ((j8 ^ (rr & 7)) << 3)],
                   &QP[w * 32 + c * 8][0]);
    }
    __syncthreads();

    bf16x8 qf[2][2];
    for (int t = 0; t < 2; ++t)
        for (int ks = 0; ks < 2; ++ks)
            qf[t][ks] = *reinterpret_cast<const bf16x8*>(
                &QP[w * 32 + t * 16 + col][((ks * 4 + quad) ^ (col & 7)) << 3]);

    f32x4 oacc[2][4] = {};
    f32x4 lacc[2] = {};

    for (int kt = 0; kt < 32; ++kt) {
        int k0 = kt * 64;
        for (int c = 0; c < 2; ++c) {
            int rr = w * 16 + c * 8 + l8;
            int sw = (j8 ^ (rr & 7)) << 3;
            async_cp16(&k_ws[((size_t)bh * Nn + k0 + rr) * D + sw], &Ks[w * 16 + c * 8][0]);
            async_cp16(&v_ws[((size_t)bh * D + rr) * Nn + k0 + sw], &Vt[w * 16 + c * 8][0]);
        }
        int pflag = pflags[b * 32 + kt];
        if (pflag && tid < 64) padb[tid] = (padding[b * Nn + k0 + tid] > 0) ? NEG : 0.f;
        __syncthreads();

        f32x4 sacc[4][2] = {};
        for (int ks = 0; ks < 2; ++ks) {
            bf16x8 kf[4];
            for (int mt = 0; mt < 4; ++mt)
                kf[mt] = *reinterpret_cast<const bf16x8*>(
                    &Ks[mt * 16 + col][((ks * 4 + quad) ^ (col & 7)) << 3]);
            for (int mt = 0; mt < 4; ++mt)
                for (int t = 0; t < 2; ++t)
                    sacc[mt][t] = __builtin_amdgcn_mfma_f32_16x16x32_bf16(kf[mt], qf[t][ks], sacc[mt][t], 0, 0, 0);
        }

        if (!aflags[qt * 32 + kt]) {
            for (int mt = 0; mt < 4; ++mt)
                for (int t = 0; t < 2; ++t)
                    for (int r = 0; r < 4; ++r) {
                        int kc = k0 + mt * 16 + quad * 4 + r;
                        int qr = q0 + w * 32 + t * 16 + col;
                        if (attn_mask[(size_t)qr * Nn + kc] == 0) sacc[mt][t][r] = NEG;
                    }
        }
        if (pflag) {
            for (int mt = 0; mt < 4; ++mt) {
                f32x4 pb = *reinterpret_cast<const f32x4*>(&padb[mt * 16 + quad * 4]);
                for (int t = 0; t < 2; ++t)
                    for (int r = 0; r < 4; ++r) sacc[mt][t][r] += pb[r];
            }
        }

        for (int t = 0; t < 2; ++t) {
            int qrow = w * 32 + t * 16 + col;
            for (int mt = 0; mt < 4; ++mt) {
                f32x4 e;
                e[0] = __builtin_amdgcn_exp2f(sacc[mt][t][0]);
                e[1] = __builtin_amdgcn_exp2f(sacc[mt][t][1]);
                e[2] = __builtin_amdgcn_exp2f(sacc[mt][t][2]);
                e[3] = __builtin_amdgcn_exp2f(sacc[mt][t][3]);
                lacc[t] += e;
                unsigned p0 = pack_bf16_2(e[0], e[1]);
                unsigned p1 = pack_bf16_2(e[2], e[3]);
                int chunk = (mt * 2 + (quad >> 1)) ^ (col & 7);
                *reinterpret_cast<uint2*>(&QP[qrow][(chunk << 3) + ((quad & 1) << 2)]) =
                    make_uint2(p0, p1);
            }
        }

        for (int ks = 0; ks < 2; ++ks) {
            bf16x8 pf[2], vf[4];
            for (int t = 0; t < 2; ++t)
                pf[t] = *reinterpret_cast<const bf16x8*>(
                    &QP[w * 32 + t * 16 + col][((ks * 4 + quad) ^ (col & 7)) << 3]);
            for (int nt = 0; nt < 4; ++nt)
                vf[nt] = *reinterpret_cast<const bf16x8*>(
                    &Vt[nt * 16 + col][((ks * 4 + quad) ^ (col & 7)) << 3]);
            for (int t = 0; t < 2; ++t)
                for (int nt = 0; nt < 4; ++nt)
                    oacc[t][nt] = __builtin_amdgcn_mfma_f32_16x16x32_bf16(pf[t], vf[nt], oacc[t][nt], 0, 0, 0);
        }
        __syncthreads();
    }

    for (int t = 0; t < 2; ++t) {
        float ls = lacc[t][0] + lacc[t][1] + lacc[t][2] + lacc[t][3];
        ls += __shfl_xor(ls, 16);
        ls += __shfl_xor(ls, 32);
        for (int r = 0; r < 4; ++r) {
            float lv = __shfl(ls, quad * 4 + r, 16);
            float inv = 1.f / lv;
            int n = q0 + w * 32 + t * 16 + quad * 4 + r;
            for (int nt = 0; nt < 4; ++nt) {
                int dd = nt * 16 + col;
                xb[((size_t)(b * Nn + n)) * 1024 + h * 64 + dd] = f2bf(oacc[t][nt][r] * inv);
            }
        }
    }
}

// ---------------------------------------------------------------------------
extern "C" void kernel_launch(void* const* d_in, const int* in_sizes, int n_in,
                              void* d_out, int out_size, void* d_ws, size_t ws_size,
                              hipStream_t stream) {
    const float* x        = (const float*)d_in[0];   // (4,2048,1024) fp32
    const int* attn_mask  = (const int*)d_in[1];     // (2048,2048)
    const int* padding    = (const int*)d_in[2];     // (4,2048)
    const float* W_qkv    = (const float*)d_in[3];   // (1024,3072)
    const float* W_proj   = (const float*)d_in[4];   // (1024,1024)
    const float* b_proj   = (const float*)d_in[5];   // (1024,)
    float* out            = (float*)d_out;

    char* ws = (char*)d_ws;
    short* Xb   = (short*)(ws);                 // 16 MB  (8192x1024 bf16)
    short* Wqt  = (short*)(ws + (16u << 20));   // 6 MB   (3072x1024 bf16, W_qkv^T)
    short* Wpt  = (short*)(ws + (22u << 20));   // 2 MB   (1024x1024 bf16, W_proj^T)
    short* q_ws = (short*)(ws + (24u << 20));   // 16 MB  (64,2048,64) pre-scaled (exp2 dom.)
    short* k_ws = (short*)(ws + (40u << 20));   // 16 MB  (64,2048,64)
    short* v_ws = (short*)(ws + (56u << 20));   // 16 MB  (64,64,2048) transposed
    short* xbuf = (short*)(ws + (72u << 20));   // 16 MB  (8192x1024 bf16) attn out
    int*  flags = (int*)(ws + (88u << 20));     // attn flags [512] + pad flags [128]

    prep_fused<<<12801, 256, 0, stream>>>(x, Xb, W_qkv, Wqt, W_proj, Wpt,
                                          attn_mask, padding, flags);

    gemm256_qkv<<<dim3(3072 / 256, 8192 / 256), 512, 0, stream>>>(
        Xb, Wqt, q_ws, k_ws, v_ws);

    flash_attn<<<dim3(16, 64), 256, 0, stream>>>(
        q_ws, k_ws, v_ws, flags, flags + 512, padding, attn_mask, xbuf);

    gemm_bf16<<<dim3(1024 / 128, 8192 / 128), 256, 0, stream>>>(
        xbuf, Wpt, 1, nullptr, nullptr, nullptr, out, b_proj);
}

// Round 13
// 275.582 us; speedup vs baseline: 1.1939x; 1.0219x over previous
//
#include <hip/hip_runtime.h>

#define NEG -10000000.0f
#define QSCALE 0.18033688011112042f   // 0.125 (d^-0.5) * log2(e): softmax in exp2 domain

typedef __attribute__((ext_vector_type(8))) short bf16x8;
typedef __attribute__((ext_vector_type(4))) float f32x4;

static __device__ __forceinline__ short f2bf(float f) {
    unsigned int u = __float_as_uint(f);
    unsigned int r = (u + 0x7fffu + ((u >> 16) & 1u)) >> 16;
    return (short)r;
}

// pack two fp32 -> packed bf16x2 (round-half-up; exp outputs, ties measure-zero)
static __device__ __forceinline__ unsigned pack_bf16_2(float a, float b) {
    unsigned ua = __float_as_uint(a) + 0x8000u;
    unsigned ub = __float_as_uint(b) + 0x8000u;
    return __builtin_amdgcn_perm(ub, ua, 0x07060302u);
}

// async global->LDS, 16B per lane. lds base wave-uniform; lane i lands at +16*i.
static __device__ __forceinline__ void async_cp16(const void* g, void* l) {
    __builtin_amdgcn_global_load_lds(
        (const __attribute__((address_space(1))) unsigned int*)g,
        (__attribute__((address_space(3))) unsigned int*)l, 16, 0, 0);
}

// ---------------------------------------------------------------------------
// R14: all prep work in ONE launch. Block ranges:
//   [0,8192) cvt_bf16 · [8192,12288) weight transposes · [12288,12801) flags
// ---------------------------------------------------------------------------
__global__ void prep_fused(const float* __restrict__ x, short* __restrict__ Xb,
                           const float* __restrict__ W_qkv, short* __restrict__ Wqt,
                           const float* __restrict__ W_proj, short* __restrict__ Wpt,
                           const int* __restrict__ attn_mask,
                           const int* __restrict__ padding, int* __restrict__ flags) {
    __shared__ float tile[32][33];
    __shared__ int blockok;
    int blk = blockIdx.x, tid = threadIdx.x;

    if (blk < 8192) {                      // ---- cvt_bf16 (n4 = 2097152 exact)
        int i = blk * 256 + tid;
        float4 v = reinterpret_cast<const float4*>(x)[i];
        short4 o;
        o.x = f2bf(v.x); o.y = f2bf(v.y); o.z = f2bf(v.z); o.w = f2bf(v.w);
        reinterpret_cast<short4*>(Xb)[i] = o;
        return;
    }
    if (blk < 12288) {                     // ---- weight transposes (4096 blocks)
        int local = blk - 8192;
        int bxi = local & 127, byi = local >> 7;       // old grid (128, 32)
        const float* src; short* dst; int cols, bxx;
        if (bxi < 96) { src = W_qkv; dst = Wqt; cols = 3072; bxx = bxi; }
        else          { src = W_proj; dst = Wpt; cols = 1024; bxx = bxi - 96; }
        int bx = bxx * 32, by = byi * 32;
        int tx = tid & 31, ty = tid >> 5;
        for (int j = 0; j < 4; ++j)
            tile[ty + j * 8][tx] = src[(size_t)(by + ty + j * 8) * cols + bx + tx];
        __syncthreads();
        for (int j = 0; j < 4; ++j)
            dst[(size_t)(bx + ty + j * 8) * 1024 + by + tx] = f2bf(tile[tx][ty + j * 8]);
        return;
    }
    int mblk = blk - 12288;                // ---- mask_flags (513 blocks)
    if (mblk == 512) {                     // fused pad_flags
        if (tid < 128) {
            int b = tid >> 5, kt = tid & 31;
            int any = 0;
            for (int j = 0; j < 64; ++j) any |= (padding[b * 2048 + kt * 64 + j] > 0);
            flags[512 + tid] = any;
        }
        return;
    }
    int qt = mblk >> 5, kt = mblk & 31;
    if (tid == 0) blockok = 1;
    __syncthreads();
    int ok = 1;
    for (int j = 0; j < 32; ++j) {
        int idx = j * 256 + tid;
        int qr = qt * 128 + (idx >> 6);
        int kc = kt * 64 + (idx & 63);
        ok &= (attn_mask[(size_t)qr * 2048 + kc] != 0);
    }
    if (!ok) blockok = 0;
    __syncthreads();
    if (tid == 0) flags[mblk] = blockok;
}

// ---------------------------------------------------------------------------
// R11/R12 (proven): 256x256x64 QKV GEMM, two-phase counted-vmcnt pipeline.
// LOCKED — byte-identical to the 281.6 us build.
// ---------------------------------------------------------------------------
#define G256_STAGE(BUF, MAT, HALF, C, KT, SRC, BASE)                              \
    {                                                                             \
        int rr_ = (HALF) * 128 + (C) * 64 + w * 8 + l8;                           \
        async_cp16(&SRC[(size_t)((BASE) + rr_) * 1024 + (KT) * 64 +               \
                        ((j8 ^ (rr_ & 7)) << 3)],                                 \
                   &smem[BUF][MAT][(HALF) * 128 + (C) * 64 + w * 8][0]);          \
    }

__global__ __launch_bounds__(512, 2) void gemm256_qkv(
    const short* __restrict__ A, const short* __restrict__ Bt,
    short* __restrict__ q_ws, short* __restrict__ k_ws, short* __restrict__ v_ws) {
    __shared__ __align__(16) short smem[2][2][256][64];   // [buf][A/B][row][k] 128 KB

    int tid = threadIdx.x, lane = tid & 63, w = tid >> 6;   // 8 waves
    int wm = w & 1, wn = w >> 1;                            // 2M x 4N
    int col = lane & 15, quad = lane >> 4;
    int l8 = lane >> 3, j8 = lane & 7;

    // T1: XCD swizzle (384 blocks, %8==0 -> bijective)
    int nwg = gridDim.x * gridDim.y;
    int hw = blockIdx.y * gridDim.x + blockIdx.x;
    int logical = (hw & 7) * (nwg >> 3) + (hw >> 3);
    int bx = logical % gridDim.x, by = logical / gridDim.x;
    int m0 = by * 256, n0 = bx * 256;

    f32x4 acc[8][4] = {};

    // prologue: stage tile 0 into buf 0 (8 loads/thread-slice)
    G256_STAGE(0, 0, 0, 0, 0, A, m0) G256_STAGE(0, 0, 0, 1, 0, A, m0)
    G256_STAGE(0, 1, 0, 0, 0, Bt, n0) G256_STAGE(0, 1, 0, 1, 0, Bt, n0)
    G256_STAGE(0, 1, 1, 0, 0, Bt, n0) G256_STAGE(0, 1, 1, 1, 0, Bt, n0)
    G256_STAGE(0, 0, 1, 0, 0, A, m0) G256_STAGE(0, 0, 1, 1, 0, A, m0)

    for (int t = 0; t < 16; ++t) {
        int bt = t & 1, nb_ = bt ^ 1, ktn = t + 1;

        // ---- P1 ----
        if (t < 15) {
            G256_STAGE(nb_, 0, 0, 0, ktn, A, m0) G256_STAGE(nb_, 0, 0, 1, ktn, A, m0)
            G256_STAGE(nb_, 1, 0, 0, ktn, Bt, n0) G256_STAGE(nb_, 1, 0, 1, ktn, Bt, n0)
            asm volatile("s_waitcnt vmcnt(4)" ::: "memory");
        } else {
            asm volatile("s_waitcnt vmcnt(0)" ::: "memory");
        }
        __builtin_amdgcn_s_barrier();
        __builtin_amdgcn_sched_barrier(0);

        bf16x8 bfr[4][2], af[4][2];
        for (int nt = 0; nt < 4; ++nt)
            for (int ks = 0; ks < 2; ++ks)
                bfr[nt][ks] = *reinterpret_cast<const bf16x8*>(
                    &smem[bt][1][wn * 64 + nt * 16 + col][((ks * 4 + quad) ^ (col & 7)) << 3]);
        for (int mt = 0; mt < 4; ++mt)
            for (int ks = 0; ks < 2; ++ks)
                af[mt][ks] = *reinterpret_cast<const bf16x8*>(
                    &smem[bt][0][wm * 128 + mt * 16 + col][((ks * 4 + quad) ^ (col & 7)) << 3]);
        __builtin_amdgcn_s_setprio(1);
        for (int ks = 0; ks < 2; ++ks)
            for (int mt = 0; mt < 4; ++mt)
                for (int nt = 0; nt < 4; ++nt)
                    acc[mt][nt] = __builtin_amdgcn_mfma_f32_16x16x32_bf16(af[mt][ks], bfr[nt][ks], acc[mt][nt], 0, 0, 0);
        __builtin_amdgcn_s_setprio(0);

        // ---- P2 ----
        if (t < 15) {
            G256_STAGE(nb_, 1, 1, 0, ktn, Bt, n0) G256_STAGE(nb_, 1, 1, 1, ktn, Bt, n0)
            G256_STAGE(nb_, 0, 1, 0, ktn, A, m0) G256_STAGE(nb_, 0, 1, 1, ktn, A, m0)
        }
        for (int mt = 0; mt < 4; ++mt)
            for (int ks = 0; ks < 2; ++ks)
                af[mt][ks] = *reinterpret_cast<const bf16x8*>(
                    &smem[bt][0][wm * 128 + (4 + mt) * 16 + col][((ks * 4 + quad) ^ (col & 7)) << 3]);
        __builtin_amdgcn_s_setprio(1);
        for (int ks = 0; ks < 2; ++ks)
            for (int mt = 0; mt < 4; ++mt)
                for (int nt = 0; nt < 4; ++nt)
                    acc[4 + mt][nt] = __builtin_amdgcn_mfma_f32_16x16x32_bf16(af[mt][ks], bfr[nt][ks], acc[4 + mt][nt], 0, 0, 0);
        __builtin_amdgcn_s_setprio(0);
        __builtin_amdgcn_sched_barrier(0);
        __builtin_amdgcn_s_barrier();   // all reads retired (consumed) -> next stage safe
    }

    // epilogue: L = 256x256 bf16 view of the whole 128 KB smem.
    short* L = &smem[0][0][0][0];
    int which = n0 >> 10;                // 0=Q 1=K 2=V
    int cb = n0 & 1023;
    int b = m0 >> 11, nb = m0 & 2047, hb = cb >> 6;

    if (which == 2) {
        // V -> [bh][dd][n]: store transposed Lt[c][m], m-chunks rotated by c
        for (int mt = 0; mt < 8; ++mt)
            for (int nt = 0; nt < 4; ++nt) {
                int ml = wm * 128 + mt * 16 + quad * 4;
                int cl = wn * 64 + nt * 16 + col;
                int mp = (ml + 8 * cl) & 255;
                short4 pk;
                for (int r = 0; r < 4; ++r) ((short*)&pk)[r] = f2bf(acc[mt][nt][r]);
                *reinterpret_cast<short4*>(&L[cl * 256 + mp]) = pk;
            }
        __syncthreads();
        for (int it = 0; it < 16; ++it) {
            int chunk = it * 512 + tid;            // 256 c-rows x 32 chunks
            int c = chunk >> 5, j = chunk & 31;
            int h = hb + (c >> 6), dd = c & 63;
            int4 val = *reinterpret_cast<const int4*>(&L[c * 256 + (((j + c) & 31) << 3)]);
            *reinterpret_cast<int4*>(
                &v_ws[((size_t)((b * 16 + h) * 64 + dd)) * 2048 + nb + j * 8]) = val;
        }
    } else {
        short* dst = (which == 0) ? q_ws : k_ws;
        float scl = (which == 0) ? QSCALE : 1.0f;
        for (int mt = 0; mt < 8; ++mt)
            for (int nt = 0; nt < 4; ++nt)
                for (int r = 0; r < 4; ++r) {
                    int ml = wm * 128 + mt * 16 + quad * 4 + r;
                    int cl = wn * 64 + nt * 16 + col;
                    L[ml * 256 + ((cl + 8 * ml) & 255)] = f2bf(acc[mt][nt][r] * scl);
                }
        __syncthreads();
        for (int it = 0; it < 16; ++it) {
            int chunk = it * 512 + tid;            // 256 rows x 32 chunks
            int row = chunk >> 5, j = chunk & 31;
            int h = hb + (j >> 3), dd = (j & 7) * 8;
            int4 val = *reinterpret_cast<const int4*>(&L[row * 256 + (((j + row) & 31) << 3)]);
            *reinterpret_cast<int4*>(
                &dst[((size_t)(b * 16 + h) * 2048 + nb + row) * 64 + dd]) = val;
        }
    }
}

// ---------------------------------------------------------------------------
// proj GEMM: 128x128x64 m97 structure, 512 blocks = 2/CU. LOCKED.
// ---------------------------------------------------------------------------
__global__ __launch_bounds__(256, 2) void gemm_bf16(
    const short* __restrict__ A, const short* __restrict__ Bt, int mode,
    short* __restrict__ q_ws, short* __restrict__ k_ws, short* __restrict__ v_ws,
    float* __restrict__ out, const float* __restrict__ bias) {
    const int K = 1024;
    __shared__ __align__(16) short smem[2][128][64];   // As/Bs, reused by epilogue
    short (*As)[64] = smem[0];
    short (*Bs)[64] = smem[1];
    int tid = threadIdx.x, lane = tid & 63, w = tid >> 6;
    int wm = w & 1, wn = w >> 1;

    int nwg = gridDim.x * gridDim.y;
    int hw = blockIdx.y * gridDim.x + blockIdx.x;
    int logical = (hw & 7) * (nwg >> 3) + (hw >> 3);
    int bx = logical % gridDim.x, by = logical / gridDim.x;
    int m0 = by * 128, n0 = bx * 128;

    int col = lane & 15, quad = lane >> 4;
    int l8 = lane >> 3, j8 = lane & 7;

    f32x4 acc[4][4] = {};

    for (int k0 = 0; k0 < K; k0 += 64) {
        for (int c = 0; c < 4; ++c) {
            int rr = w * 32 + c * 8 + l8;
            int sw = (j8 ^ (rr & 7)) << 3;
            async_cp16(&A[(size_t)(m0 + rr) * K + k0 + sw], &As[w * 32 + c * 8][0]);
            async_cp16(&Bt[(size_t)(n0 + rr) * K + k0 + sw], &Bs[w * 32 + c * 8][0]);
        }
        __syncthreads();
        for (int ks = 0; ks < 2; ++ks) {
            bf16x8 af[4], bfr[4];
            for (int mt = 0; mt < 4; ++mt)
                af[mt] = *reinterpret_cast<const bf16x8*>(
                    &As[wm * 64 + mt * 16 + col][((ks * 4 + quad) ^ (col & 7)) << 3]);
            for (int nt = 0; nt < 4; ++nt)
                bfr[nt] = *reinterpret_cast<const bf16x8*>(
                    &Bs[wn * 64 + nt * 16 + col][((ks * 4 + quad) ^ (col & 7)) << 3]);
            for (int mt = 0; mt < 4; ++mt)
                for (int nt = 0; nt < 4; ++nt)
                    acc[mt][nt] = __builtin_amdgcn_mfma_f32_16x16x32_bf16(af[mt], bfr[nt], acc[mt][nt], 0, 0, 0);
        }
        __syncthreads();
    }

    short* L = &smem[0][0][0];   // 128x128 bf16 view (32 KB)

    if (mode == 0) {
        int which = n0 >> 10;
        int cb = n0 & 1023;
        int b = m0 >> 11, nb = m0 & 2047, hb = cb >> 6;
        if (which == 2) {
            for (int mt = 0; mt < 4; ++mt)
                for (int nt = 0; nt < 4; ++nt) {
                    int ml = wm * 64 + mt * 16 + quad * 4;
                    int cl = wn * 64 + nt * 16 + col;
                    int mp = (ml + 8 * cl) & 127;
                    short4 pk;
                    for (int r = 0; r < 4; ++r) ((short*)&pk)[r] = f2bf(acc[mt][nt][r]);
                    *reinterpret_cast<short4*>(&L[cl * 128 + mp]) = pk;
                }
            __syncthreads();
            for (int it = 0; it < 8; ++it) {
                int chunk = it * 256 + tid;
                int c = chunk >> 4, j = chunk & 15;
                int h = hb + (c >> 6), dd = c & 63;
                int4 val = *reinterpret_cast<const int4*>(&L[c * 128 + (((j + c) & 15) << 3)]);
                *reinterpret_cast<int4*>(
                    &v_ws[((size_t)((b * 16 + h) * 64 + dd)) * 2048 + nb + j * 8]) = val;
            }
        } else {
            short* dst = (which == 0) ? q_ws : k_ws;
            float scl = (which == 0) ? QSCALE : 1.0f;
            for (int mt = 0; mt < 4; ++mt)
                for (int nt = 0; nt < 4; ++nt)
                    for (int r = 0; r < 4; ++r) {
                        int ml = wm * 64 + mt * 16 + quad * 4 + r;
                        int cl = wn * 64 + nt * 16 + col;
                        L[ml * 128 + ((cl + 8 * ml) & 127)] = f2bf(acc[mt][nt][r] * scl);
                    }
            __syncthreads();
            for (int it = 0; it < 8; ++it) {
                int chunk = it * 256 + tid;
                int row = chunk >> 4, j = chunk & 15;
                int h = hb + (j >> 3), dd = (j & 7) * 8;
                int4 val = *reinterpret_cast<const int4*>(&L[row * 128 + (((j + row) & 15) << 3)]);
                *reinterpret_cast<int4*>(
                    &dst[((size_t)(b * 16 + h) * 2048 + nb + row) * 64 + dd]) = val;
            }
        }
    } else {
        float* Lf = reinterpret_cast<float*>(L);       // 64 x 128 fp32
        for (int half = 0; half < 2; ++half) {
            if (wm == half) {
                for (int mt = 0; mt < 4; ++mt)
                    for (int nt = 0; nt < 4; ++nt)
                        for (int r = 0; r < 4; ++r) {
                            int ml = mt * 16 + quad * 4 + r;
                            int cl = wn * 64 + nt * 16 + col;
                            Lf[ml * 128 + cl] = acc[mt][nt][r];
                        }
            }
            __syncthreads();
            for (int it = 0; it < 8; ++it) {
                int chunk = it * 256 + tid;
                int row = chunk >> 5, j = chunk & 31;
                float4 val = *reinterpret_cast<const float4*>(&Lf[row * 128 + j * 4]);
                float4 bv = *reinterpret_cast<const float4*>(&bias[n0 + j * 4]);
                val.x += bv.x; val.y += bv.y; val.z += bv.z; val.w += bv.w;
                *reinterpret_cast<float4*>(
                    &out[(size_t)(m0 + half * 64 + row) * 1024 + n0 + j * 4]) = val;
            }
            __syncthreads();
        }
    }
}

// ---------------------------------------------------------------------------
// Flash attention, R17: bigger Q-tile, SAME per-wave shape. 512 thr = 8 waves
// x 32 qrows = 256-row Q-tile (grid (8,64) = 512 blocks = 2/CU exact).
// Each wave's inner code is byte-identical to the locked R6 wave (qf[2][2],
// 16+16 MFMAs, P-via-LDS, same swizzles, 2 __syncthreads/iter, no asm).
// What changes vs R6: per unit work, barrier drains / staging issues / KV
// refetch all HALVE (32-iter K/V sweep serves 256 rows, not 128; each wave
// stages 8 K-rows + 8 V-rows per iter, was 16+16). Per-wave LDS-read
// amortization unchanged (R8's failure mode avoided). LDS 48.3 KB;
// aflags (128-row granularity) AND-combined per 256-row tile.
// ---------------------------------------------------------------------------
__global__ __launch_bounds__(512, 4) void flash_attn(
    const short* __restrict__ q_ws, const short* __restrict__ k_ws,
    const short* __restrict__ v_ws, const int* __restrict__ aflags,
    const int* __restrict__ pflags, const int* __restrict__ padding,
    const int* __restrict__ attn_mask, short* __restrict__ xb) {
    const int Nn = 2048, D = 64;
    __shared__ short QP[256][64];   // Q staging, then P tile (wave-private 32-row bands)
    __shared__ short Ks[64][64];
    __shared__ short Vt[64][64];    // V^T: [d][kcol]
    __shared__ __align__(16) float padb[64];

    int tid = threadIdx.x, lane = tid & 63, w = tid >> 6;   // w = 0..7
    int col = lane & 15, quad = lane >> 4;

    // T1: XCD swizzle (512 blocks, %8==0 -> bijective). XCD k owns bh 8k..8k+7
    // (all 8 q-tiles each) -> co-resident KV working set 4 MB = L2 capacity.
    int hw = blockIdx.y * 8 + blockIdx.x;
    int logical = (hw & 7) * 64 + (hw >> 3);
    int bh = logical >> 3, qt = logical & 7;
    int b = bh >> 4, h = bh & 15;
    int q0 = qt * 256;

    int l8 = lane >> 3, j8 = lane & 7;

    // stage Q (swizzled gather -> linear lane-ordered LDS): 32 rows per wave
    for (int c = 0; c < 4; ++c) {
        int rr = w * 32 + c * 8 + l8;
        async_cp16(&q_ws[((size_t)bh * Nn + q0 + rr) * D + ((j8 ^ (rr & 7)) << 3)],
                   &QP[w * 32 + c * 8][0]);
    }
    __syncthreads();

    // persistent Q B-frags; QP rows w*32..+31 are wave-private from here on
    bf16x8 qf[2][2];
    for (int t = 0; t < 2; ++t)
        for (int ks = 0; ks < 2; ++ks)
            qf[t][ks] = *reinterpret_cast<const bf16x8*>(
                &QP[w * 32 + t * 16 + col][((ks * 4 + quad) ^ (col & 7)) << 3]);

    f32x4 oacc[2][4] = {};
    f32x4 lacc[2] = {};

    for (int kt = 0; kt < 32; ++kt) {
        int k0 = kt * 64;
        {
            int rr = w * 8 + l8;                       // 8 rows per wave per matrix
            int sw = (j8 ^ (rr & 7)) << 3;
            async_cp16(&k_ws[((size_t)bh * Nn + k0 + rr) * D + sw], &Ks[w * 8][0]);
            async_cp16(&v_ws[((size_t)bh * D + rr) * Nn + k0 + sw], &Vt[w * 8][0]);
        }
        int pflag = pflags[b * 32 + kt];
        if (pflag && tid < 64) padb[tid] = (padding[b * Nn + k0 + tid] > 0) ? NEG : 0.f;
        __syncthreads();

        f32x4 sacc[4][2] = {};
        for (int ks = 0; ks < 2; ++ks) {
            bf16x8 kf[4];
            for (int mt = 0; mt < 4; ++mt)
                kf[mt] = *reinterpret_cast<const bf16x8*>(
                    &Ks[mt * 16 + col][((ks * 4 + quad) ^ (col & 7)) << 3]);
            for (int mt = 0; mt < 4; ++mt)
                for (int t = 0; t < 2; ++t)
                    sacc[mt][t] = __builtin_amdgcn_mfma_f32_16x16x32_bf16(kf[mt], qf[t][ks], sacc[mt][t], 0, 0, 0);
        }

        // aflags are per 128-row q-tile: AND the two subtiles of this 256-row tile
        if (!(aflags[(qt * 2) * 32 + kt] & aflags[(qt * 2 + 1) * 32 + kt])) {
            for (int mt = 0; mt < 4; ++mt)
                for (int t = 0; t < 2; ++t)
                    for (int r = 0; r < 4; ++r) {
                        int kc = k0 + mt * 16 + quad * 4 + r;
                        int qr = q0 + w * 32 + t * 16 + col;
                        if (attn_mask[(size_t)qr * Nn + kc] == 0) sacc[mt][t][r] = NEG;
                    }
        }
        if (pflag) {
            for (int mt = 0; mt < 4; ++mt) {
                f32x4 pb = *reinterpret_cast<const f32x4*>(&padb[mt * 16 + quad * 4]);
                for (int t = 0; t < 2; ++t)
                    for (int r = 0; r < 4; ++r) sacc[mt][t][r] += pb[r];
            }
        }

        for (int t = 0; t < 2; ++t) {
            int qrow = w * 32 + t * 16 + col;
            for (int mt = 0; mt < 4; ++mt) {
                f32x4 e;
                e[0] = __builtin_amdgcn_exp2f(sacc[mt][t][0]);
                e[1] = __builtin_amdgcn_exp2f(sacc[mt][t][1]);
                e[2] = __builtin_amdgcn_exp2f(sacc[mt][t][2]);
                e[3] = __builtin_amdgcn_exp2f(sacc[mt][t][3]);
                lacc[t] += e;
                unsigned p0 = pack_bf16_2(e[0], e[1]);
                unsigned p1 = pack_bf16_2(e[2], e[3]);
                int chunk = (mt * 2 + (quad >> 1)) ^ (col & 7);
                *reinterpret_cast<uint2*>(&QP[qrow][(chunk << 3) + ((quad & 1) << 2)]) =
                    make_uint2(p0, p1);
            }
        }

        for (int ks = 0; ks < 2; ++ks) {
            bf16x8 pf[2], vf[4];
            for (int t = 0; t < 2; ++t)
                pf[t] = *reinterpret_cast<const bf16x8*>(
                    &QP[w * 32 + t * 16 + col][((ks * 4 + quad) ^ (col & 7)) << 3]);
            for (int nt = 0; nt < 4; ++nt)
                vf[nt] = *reinterpret_cast<const bf16x8*>(
                    &Vt[nt * 16 + col][((ks * 4 + quad) ^ (col & 7)) << 3]);
            for (int t = 0; t < 2; ++t)
                for (int nt = 0; nt < 4; ++nt)
                    oacc[t][nt] = __builtin_amdgcn_mfma_f32_16x16x32_bf16(pf[t], vf[nt], oacc[t][nt], 0, 0, 0);
        }
        __syncthreads();
    }

    for (int t = 0; t < 2; ++t) {
        float ls = lacc[t][0] + lacc[t][1] + lacc[t][2] + lacc[t][3];
        ls += __shfl_xor(ls, 16);
        ls += __shfl_xor(ls, 32);
        for (int r = 0; r < 4; ++r) {
            float lv = __shfl(ls, quad * 4 + r, 16);
            float inv = 1.f / lv;
            int n = q0 + w * 32 + t * 16 + quad * 4 + r;
            for (int nt = 0; nt < 4; ++nt) {
                int dd = nt * 16 + col;
                xb[((size_t)(b * Nn + n)) * 1024 + h * 64 + dd] = f2bf(oacc[t][nt][r] * inv);
            }
        }
    }
}

// ---------------------------------------------------------------------------
extern "C" void kernel_launch(void* const* d_in, const int* in_sizes, int n_in,
                              void* d_out, int out_size, void* d_ws, size_t ws_size,
                              hipStream_t stream) {
    const float* x        = (const float*)d_in[0];   // (4,2048,1024) fp32
    const int* attn_mask  = (const int*)d_in[1];     // (2048,2048)
    const int* padding    = (const int*)d_in[2];     // (4,2048)
    const float* W_qkv    = (const float*)d_in[3];   // (1024,3072)
    const float* W_proj   = (const float*)d_in[4];   // (1024,1024)
    const float* b_proj   = (const float*)d_in[5];   // (1024,)
    float* out            = (float*)d_out;

    char* ws = (char*)d_ws;
    short* Xb   = (short*)(ws);                 // 16 MB  (8192x1024 bf16)
    short* Wqt  = (short*)(ws + (16u << 20));   // 6 MB   (3072x1024 bf16, W_qkv^T)
    short* Wpt  = (short*)(ws + (22u << 20));   // 2 MB   (1024x1024 bf16, W_proj^T)
    short* q_ws = (short*)(ws + (24u << 20));   // 16 MB  (64,2048,64) pre-scaled (exp2 dom.)
    short* k_ws = (short*)(ws + (40u << 20));   // 16 MB  (64,2048,64)
    short* v_ws = (short*)(ws + (56u << 20));   // 16 MB  (64,64,2048) transposed
    short* xbuf = (short*)(ws + (72u << 20));   // 16 MB  (8192x1024 bf16) attn out
    int*  flags = (int*)(ws + (88u << 20));     // attn flags [512] + pad flags [128]

    prep_fused<<<12801, 256, 0, stream>>>(x, Xb, W_qkv, Wqt, W_proj, Wpt,
                                          attn_mask, padding, flags);

    gemm256_qkv<<<dim3(3072 / 256, 8192 / 256), 512, 0, stream>>>(
        Xb, Wqt, q_ws, k_ws, v_ws);

    flash_attn<<<dim3(8, 64), 512, 0, stream>>>(
        q_ws, k_ws, v_ws, flags, flags + 512, padding, attn_mask, xbuf);

    gemm_bf16<<<dim3(1024 / 128, 8192 / 128), 256, 0, stream>>>(
        xbuf, Wpt, 1, nullptr, nullptr, nullptr, out, b_proj);
}